// Round 18
// baseline (467.310 us; speedup 1.0000x reference)
//
#include <hip/hip_runtime.h>
#include <math.h>

#define DEV static __device__ __forceinline__

// ---- ordered-uint encoding for float atomic max ----
DEV unsigned fenc(float f) {
    unsigned u = __float_as_uint(f);
    return (u & 0x80000000u) ? ~u : (u | 0x80000000u);
}
DEV float fdec(unsigned u) {
    return __uint_as_float((u & 0x80000000u) ? (u ^ 0x80000000u) : ~u);
}
DEV void atomic_max_u32(unsigned* p, unsigned v) {
    __hip_atomic_fetch_max(p, v, __ATOMIC_RELAXED, __HIP_MEMORY_SCOPE_AGENT);
}
// ---- bf16 helpers (RNE) ----
DEV unsigned bf16(float f) {
    unsigned u = __float_as_uint(f);
    return (u + 0x7FFFu + ((u >> 16) & 1u)) >> 16;
}
DEV float unbf16(unsigned s) { return __uint_as_float(s << 16); }

// ================= layer-1 projection (K=5) fused with attn terms =================
// xpb: [N][16][6] bf16 record = {f0..f4, sterm}; 12B/head (192B/node), 4B-aligned.
__global__ void k_proj5t(const float* __restrict__ x, const float* __restrict__ W,
                         const float* __restrict__ a_s, const float* __restrict__ a_d,
                         unsigned short* __restrict__ xpb, float* __restrict__ dterm, int N) {
    int i = blockIdx.x * blockDim.x + threadIdx.x;   // n*16 + h
    if (i >= N * 16) return;
    int n = i >> 4, h = i & 15;
    float xr[5];
    #pragma unroll
    for (int j = 0; j < 5; ++j) xr[j] = x[(size_t)n * 5 + j];
    float o[5];
    #pragma unroll
    for (int c = 0; c < 5; ++c) {
        const float* wr = W + (size_t)(h * 5 + c) * 5;
        float s = 0.f;
        #pragma unroll
        for (int j = 0; j < 5; ++j) s += xr[j] * wr[j];
        o[c] = s;
    }
    float ss = 0.f, sd = 0.f;
    #pragma unroll
    for (int c = 0; c < 5; ++c) { ss += o[c] * a_s[h * 5 + c]; sd += o[c] * a_d[h * 5 + c]; }
    unsigned* p = (unsigned*)(xpb + (size_t)n * 96 + h * 6);
    p[0] = bf16(o[0]) | (bf16(o[1]) << 16);
    p[1] = bf16(o[2]) | (bf16(o[3]) << 16);
    p[2] = bf16(o[4]) | (bf16(ss) << 16);
    dterm[i] = sd;
}

// ================= layer-2 projection (K=80) : LDS-tiled GEMM, bf16 input =================
__global__ __launch_bounds__(256) void k_proj80t(
    const unsigned short* __restrict__ in,   // [N][80] bf16 (h1)
    const float* __restrict__ W,             // [80][80]
    const float* __restrict__ a_s, const float* __restrict__ a_d,
    unsigned short* __restrict__ xpb, float* __restrict__ dterm, int N) {
    __shared__ float XS[16 * 136];   // [kk][node]
    __shared__ float WS[16 * 81];    // [kk][oc]
    int tid = threadIdx.x;
    int n0 = blockIdx.x * 128;
    int h = tid & 15, ng = tid >> 4;

    float acc[8][5];
    #pragma unroll
    for (int j = 0; j < 8; ++j)
        #pragma unroll
        for (int c = 0; c < 5; ++c) acc[j][c] = 0.f;

    for (int k0 = 0; k0 < 80; k0 += 16) {
        __syncthreads();
        {   // stage XS: 8 bf16 per thread = one 16B load
            int r = tid >> 1;
            int halfk = (tid & 1) * 8;
            int n = n0 + r; if (n >= N) n = N - 1;
            const uint4 v = *(const uint4*)(in + (size_t)n * 80 + k0 + halfk);
            unsigned uu[4] = {v.x, v.y, v.z, v.w};
            #pragma unroll
            for (int j = 0; j < 4; ++j) {
                XS[(halfk + 2 * j)     * 136 + r] = unbf16(uu[j] & 0xffff);
                XS[(halfk + 2 * j + 1) * 136 + r] = unbf16(uu[j] >> 16);
            }
        }
        {   // stage WS
            #pragma unroll
            for (int i = 0; i < 5; ++i) {
                int j = tid + i * 256;
                int oc = j >> 4, kk = j & 15;
                WS[kk * 81 + oc] = W[(size_t)oc * 80 + k0 + kk];
            }
        }
        __syncthreads();
        #pragma unroll
        for (int kk = 0; kk < 16; ++kk) {
            float4 xa = *(const float4*)&XS[kk * 136 + ng * 8];
            float4 xb = *(const float4*)&XS[kk * 136 + ng * 8 + 4];
            float wv[5];
            #pragma unroll
            for (int c = 0; c < 5; ++c) wv[c] = WS[kk * 81 + h * 5 + c];
            float xv[8] = {xa.x, xa.y, xa.z, xa.w, xb.x, xb.y, xb.z, xb.w};
            #pragma unroll
            for (int j = 0; j < 8; ++j)
                #pragma unroll
                for (int c = 0; c < 5; ++c) acc[j][c] += xv[j] * wv[c];
        }
    }
    float as_[5], ad_[5];
    #pragma unroll
    for (int c = 0; c < 5; ++c) { as_[c] = a_s[h * 5 + c]; ad_[c] = a_d[h * 5 + c]; }
    #pragma unroll
    for (int j = 0; j < 8; ++j) {
        int n = n0 + ng * 8 + j;
        if (n < N) {
            float ss = 0.f, sd = 0.f;
            #pragma unroll
            for (int c = 0; c < 5; ++c) { ss += acc[j][c] * as_[c]; sd += acc[j][c] * ad_[c]; }
            unsigned* p = (unsigned*)(xpb + (size_t)n * 96 + h * 6);
            p[0] = bf16(acc[j][0]) | (bf16(acc[j][1]) << 16);
            p[1] = bf16(acc[j][2]) | (bf16(acc[j][3]) << 16);
            p[2] = bf16(acc[j][4]) | (bf16(ss) << 16);
            dterm[n * 16 + h] = sd;
        }
    }
}

// ================= CSR build: bucket counts (all + keep) -> scan -> bin -> LDS sort ====
#define BIN_TILE 4096
__global__ __launch_bounds__(256) void k_cnt512(const int* __restrict__ dst,
        const float* __restrict__ ea, int* __restrict__ bcnt, int E, int NB) {
    __shared__ int cnt[512], cnt2[512];
    int tid = threadIdx.x;
    for (int b = tid; b < NB; b += 256) { cnt[b] = 0; cnt2[b] = 0; }
    __syncthreads();
    int e0 = blockIdx.x * BIN_TILE;
    #pragma unroll
    for (int k = 0; k < BIN_TILE / 256; ++k) {
        int e = e0 + k * 256 + tid;
        if (e < E) {
            int b = ((unsigned)dst[e]) >> 8;
            atomicAdd(&cnt[b], 1);
            if (ea[2 * e] > 1.0f) atomicAdd(&cnt2[b], 1);
        }
    }
    __syncthreads();
    for (int b = tid; b < NB; b += 256) {
        if (cnt[b])  __hip_atomic_fetch_add(&bcnt[b], cnt[b], __ATOMIC_RELAXED, __HIP_MEMORY_SCOPE_AGENT);
        if (cnt2[b]) __hip_atomic_fetch_add(&bcnt[512 + b], cnt2[b], __ATOMIC_RELAXED, __HIP_MEMORY_SCOPE_AGENT);
    }
}

// single block: scan both count arrays; seed boff/bcur/boff2; write pads + off[N]/off2[N].
__global__ void k_scan512(const int* __restrict__ bcnt,
        int* __restrict__ boff, int* __restrict__ bcur, int* __restrict__ boff2,
        int* __restrict__ off, int* __restrict__ off2,
        uint2* __restrict__ erec, uint2* __restrict__ erec2, int NB, int N, int E) {
    __shared__ int sm[512], sm2[512];
    int t = threadIdx.x;
    int v  = (t < NB) ? bcnt[t] : 0;
    int v2 = (t < NB) ? bcnt[512 + t] : 0;
    sm[t] = v; sm2[t] = v2;
    __syncthreads();
    for (int s = 1; s < 512; s <<= 1) {
        int u = (t >= s) ? sm[t - s] : 0, u2 = (t >= s) ? sm2[t - s] : 0;
        __syncthreads();
        sm[t] += u; sm2[t] += u2;
        __syncthreads();
    }
    int excl = sm[t] - v, excl2 = sm2[t] - v2;
    if (t < NB) { boff[t] = excl; bcur[t] = excl; boff2[t] = excl2; }
    if (t == NB - 1) {
        int K = excl2 + v2;
        boff[NB] = excl + v; boff2[NB] = K;
        #pragma unroll
        for (int j = 0; j < 4; ++j) {                 // deep-pipeline pads
            erec[E + j] = make_uint2(0, 0);
            erec2[K + j] = make_uint2(0, 0);
        }
        off[N] = E; off2[N] = K;
    }
}

// bin edges into bucket-grouped ebuf. record: {src*192 | keep<<31, bf16ea pair, dst, 0}.
// keep = (ea0 > 1.0) evaluated EXACTLY in fp32 here.
__global__ __launch_bounds__(256) void k_bin(const int* __restrict__ src,
        const int* __restrict__ dst, const float* __restrict__ ea,
        int* __restrict__ bcur, uint4* __restrict__ ebuf, int E, int NB) {
    __shared__ int cnt[512];
    __shared__ int base[512];
    int tid = threadIdx.x;
    for (int b = tid; b < NB; b += 256) cnt[b] = 0;
    __syncthreads();
    int e0 = blockIdx.x * BIN_TILE;
    #pragma unroll
    for (int k = 0; k < BIN_TILE / 256; ++k) {
        int e = e0 + k * 256 + tid;
        if (e < E) atomicAdd(&cnt[((unsigned)dst[e]) >> 8], 1);
    }
    __syncthreads();
    for (int b = tid; b < NB; b += 256) {
        int c = cnt[b];
        base[b] = c ? __hip_atomic_fetch_add(&bcur[b], c, __ATOMIC_RELAXED,
                                             __HIP_MEMORY_SCOPE_AGENT) : 0;
        cnt[b] = 0;   // reuse as local cursor
    }
    __syncthreads();
    #pragma unroll
    for (int k = 0; k < BIN_TILE / 256; ++k) {
        int e = e0 + k * 256 + tid;
        if (e < E) {
            int d = dst[e];
            int b = ((unsigned)d) >> 8;
            int r = atomicAdd(&cnt[b], 1);
            float a0 = ea[2 * e], a1 = ea[2 * e + 1];
            unsigned ro = (unsigned)src[e] * 192u;          // byte row offset into xpb
            if (a0 > 1.0f) ro |= 0x80000000u;
            ebuf[base[b] + r] = make_uint4(ro, bf16(a0) | (bf16(a1) << 16), (unsigned)d, 0u);
        }
    }
}

// one block per bucket: per-node hists (all + keep) -> scans -> off/off2 -> scatter both.
__global__ __launch_bounds__(256) void k_perm2(const int* __restrict__ boff,
        const int* __restrict__ boff2, const uint4* __restrict__ ebuf,
        uint2* __restrict__ erec, uint2* __restrict__ erec2,
        int* __restrict__ off, int* __restrict__ off2, int N) {
    __shared__ int cA[256], sA[256], cB[256], sB[256];
    int b = blockIdx.x, tid = threadIdx.x;
    int d0 = b << 8;
    int s0 = boff[b], s1 = boff[b + 1];
    int s20 = boff2[b];
    cA[tid] = 0; cB[tid] = 0;
    __syncthreads();
    for (int i = s0 + tid; i < s1; i += 256) {
        uint4 r = ebuf[i];
        int l = (int)r.z - d0;
        atomicAdd(&cA[l], 1);
        if (r.x >> 31) atomicAdd(&cB[l], 1);
    }
    __syncthreads();
    int vA = cA[tid], vB = cB[tid];
    sA[tid] = vA; sB[tid] = vB;
    __syncthreads();
    for (int s = 1; s < 256; s <<= 1) {
        int uA = (tid >= s) ? sA[tid - s] : 0, uB = (tid >= s) ? sB[tid - s] : 0;
        __syncthreads();
        sA[tid] += uA; sB[tid] += uB;
        __syncthreads();
    }
    int eA = sA[tid] - vA, eB = sB[tid] - vB;
    if (d0 + tid < N) { off[d0 + tid] = s0 + eA; off2[d0 + tid] = s20 + eB; }
    cA[tid] = s0 + eA; cB[tid] = s20 + eB;   // cursors
    __syncthreads();
    for (int i = s0 + tid; i < s1; i += 256) {
        uint4 r = ebuf[i];
        int l = (int)r.z - d0;
        unsigned ro = r.x & 0x7fffffffu;
        int p = atomicAdd(&cA[l], 1);
        erec[p] = make_uint2(ro, r.y);
        if (r.x >> 31) {
            int p2 = atomicAdd(&cB[l], 1);
            erec2[p2] = make_uint2(ro, r.y);
        }
    }
}

// ================= fused GAT: branchless 2x-unrolled pipeline, one exp/edge =============
// record = {byte row offset into xpb, bf16 ea pair}; lists padded with 4 zero records.
// POOL: epilogue scatter-maxes into 8-sliced pool (h2 never materialized).
template<bool POOL>
__global__ void k_gat(const int* __restrict__ off, const uint2* __restrict__ erec,
                      const float* __restrict__ dterm,
                      const float* __restrict__ We, const float* __restrict__ a_e,
                      const unsigned short* __restrict__ xpb,
                      const float* __restrict__ bias, unsigned short* __restrict__ hout,
                      const float* __restrict__ x, unsigned* __restrict__ psl, int N) {
    int i = blockIdx.x * blockDim.x + threadIdx.x;   // d*16 + h
    if (i >= N * 16) return;
    int d = i >> 4, h = i & 15;
    float q0 = 0.f, q1 = 0.f;
    #pragma unroll
    for (int c = 0; c < 5; ++c) {
        float ae = a_e[h * 5 + c];
        q0 += We[(h * 5 + c) * 2 + 0] * ae;
        q1 += We[(h * 5 + c) * 2 + 1] * ae;
    }
    float dt = dterm[i];
    const char* xb = (const char*)xpb;
    int hoff = h * 12;

    float m, den = 1.f, n0, n1, n2, n3, n4;
    {
        const uint3 v = *(const uint3*)(xb + d * 192 + hoff);
        n0 = unbf16(v.x & 0xffff); n1 = unbf16(v.x >> 16);
        n2 = unbf16(v.y & 0xffff); n3 = unbf16(v.y >> 16);
        n4 = unbf16(v.z & 0xffff);
        float sl = unbf16(v.z >> 16) + dt;
        m = fmaxf(sl, 0.2f * sl);
    }

    int e0 = off[d], e1 = off[d + 1];
    uint2 ra = erec[e0], rb = erec[e0 + 1];
    uint3 va = *(const uint3*)(xb + ra.x + hoff);
    uint3 vb = *(const uint3*)(xb + rb.x + hoff);
    for (int e = e0; e < e1; e += 2) {
        uint2 rc = erec[e + 2], rd = erec[e + 3];              // pads make these safe
        uint3 vc = *(const uint3*)(xb + rc.x + hoff);
        uint3 vd = *(const uint3*)(xb + rd.x + hoff);
        {   // edge A (always valid)
            float ea0 = unbf16(ra.y & 0xffff), ea1 = unbf16(ra.y >> 16);
            float st = unbf16(va.z >> 16);
            float al = st + dt + ea0 * q0 + ea1 * q1;
            al = fmaxf(al, 0.2f * al);
            bool gt = al > m;
            float t = __expf(-fabsf(al - m));
            float c = gt ? t : 1.f;
            float w = gt ? 1.f : t;
            m = fmaxf(m, al);
            den = den * c + w;
            n0 = n0 * c + w * unbf16(va.x & 0xffff);
            n1 = n1 * c + w * unbf16(va.x >> 16);
            n2 = n2 * c + w * unbf16(va.y & 0xffff);
            n3 = n3 * c + w * unbf16(va.y >> 16);
            n4 = n4 * c + w * unbf16(va.z & 0xffff);
        }
        if (e + 1 < e1) {   // edge B
            float ea0 = unbf16(rb.y & 0xffff), ea1 = unbf16(rb.y >> 16);
            float st = unbf16(vb.z >> 16);
            float al = st + dt + ea0 * q0 + ea1 * q1;
            al = fmaxf(al, 0.2f * al);
            bool gt = al > m;
            float t = __expf(-fabsf(al - m));
            float c = gt ? t : 1.f;
            float w = gt ? 1.f : t;
            m = fmaxf(m, al);
            den = den * c + w;
            n0 = n0 * c + w * unbf16(vb.x & 0xffff);
            n1 = n1 * c + w * unbf16(vb.x >> 16);
            n2 = n2 * c + w * unbf16(vb.y & 0xffff);
            n3 = n3 * c + w * unbf16(vb.y >> 16);
            n4 = n4 * c + w * unbf16(vb.z & 0xffff);
        }
        ra = rc; rb = rd; va = vc; vb = vd;
    }
    float inv = 1.0f / den;
    const float* br = bias + h * 5;
    float v0 = n0 * inv + br[0];
    float v1 = n1 * inv + br[1];
    float v2 = n2 * inv + br[2];
    float v3 = n3 * inv + br[3];
    float v4 = n4 * inv + br[4];
    if (POOL) {
        int t = (int)x[(size_t)d * 5 + 2];           // timing bin, 0..499
        unsigned* pr = psl + (size_t)(blockIdx.x & 7) * 40000 + t * 80 + h * 5;
        atomic_max_u32(pr + 0, fenc(v0));
        atomic_max_u32(pr + 1, fenc(v1));
        atomic_max_u32(pr + 2, fenc(v2));
        atomic_max_u32(pr + 3, fenc(v3));
        atomic_max_u32(pr + 4, fenc(v4));
    } else {
        unsigned short* orow = hout + (size_t)d * 80 + h * 5;
        orow[0] = (unsigned short)bf16(v0);
        orow[1] = (unsigned short)bf16(v1);
        orow[2] = (unsigned short)bf16(v2);
        orow[3] = (unsigned short)bf16(v3);
        orow[4] = (unsigned short)bf16(v4);
    }
}

// ================= conv1: 2 instances x 16 t-chunks; slice-reduce + decode fused =======
// NOTE: z[0][ic][p] = FLAT_pooled[ic*500 + p] (reference reshape quirk). Keep FLAT index.
__global__ __launch_bounds__(256) void k_conv1(const unsigned* __restrict__ psl,
        const float* __restrict__ w, const float* __restrict__ b,
        float* __restrict__ c1) {
    __shared__ float XS[80 * 44];        // window: p in [2*t0-1, 2*t0+39]
    __shared__ float WS[16 * 972];
    int gg = blockIdx.x >> 4, chunk = blockIdx.x & 15;
    int t0 = chunk * 16;
    int tid = threadIdx.x;
    for (int idx = tid; idx < 80 * 44; idx += 256) {
        int ic = idx / 44, j = idx % 44;
        int p = 2 * t0 - 1 + j;
        float v = 0.f;
        if (gg == 0 && j < 41 && p >= 0 && p < 500) {
            int jf = ic * 500 + p;                    // FLAT index (reshape quirk)
            unsigned u = 0u;
            #pragma unroll
            for (int s = 0; s < 8; ++s) u = max(u, psl[s * 40000 + jf]);
            v = (u == 0u) ? 0.f : fdec(u);
        }
        XS[idx] = v;
    }
    for (int idx = tid; idx < 12800; idx += 256) {
        int oc = idx / 800, r = idx % 800;
        int ic = r / 10, k = r % 10;
        WS[oc * 972 + ic * 12 + k] = w[idx];
    }
    __syncthreads();
    int oc = tid >> 4, tg = tid & 15;
    float acc = 0.f;
    for (int ic = 0; ic < 80; ++ic) {
        const float* xr = &XS[ic * 44 + 2 * tg];
        const float* wr = &WS[oc * 972 + ic * 12];
        #pragma unroll
        for (int k = 0; k < 10; ++k) acc += xr[k] * wr[k];
    }
    int t = t0 + tg;
    if (t < 247) {
        float s = acc + b[oc];
        c1[(size_t)gg * 3952 + oc * 247 + t] = s >= 0.f ? s : 0.01f * s;
    }
}

// ================= conv2: block = (g,oc), one t per thread =================
__global__ __launch_bounds__(128) void k_conv2(const float* __restrict__ c1,
        const float* __restrict__ w2c, const float* __restrict__ b2c,
        float* __restrict__ c2g) {
    __shared__ float Z1[16 * 248];
    __shared__ float WS[160];
    int g = blockIdx.x >> 4, oc = blockIdx.x & 15;
    int tid = threadIdx.x;
    for (int idx = tid; idx < 16 * 247; idx += 128) {
        int ic = idx / 247, t = idx % 247;
        Z1[ic * 248 + t] = c1[(size_t)g * 3952 + idx];
    }
    for (int idx = tid; idx < 160; idx += 128) WS[idx] = w2c[oc * 160 + idx];
    __syncthreads();
    if (tid < 120) {
        float s = b2c[oc];
        #pragma unroll 4
        for (int ic = 0; ic < 16; ++ic) {
            const float* xr = &Z1[ic * 248];
            const float* wr = &WS[ic * 10];
            #pragma unroll
            for (int k = 0; k < 10; ++k) {
                int p = 2 * tid + k - 1;
                if (p >= 0 && p < 247) s += xr[p] * wr[k];
            }
        }
        c2g[g * 1920 + oc * 120 + tid] = s >= 0.f ? s : 0.01f * s;
    }
}

// ================= conv3: block = (g,oc), one t per thread =================
__global__ __launch_bounds__(128) void k_conv3(const float* __restrict__ c2g,
        const float* __restrict__ w3c, const float* __restrict__ b3c,
        float* __restrict__ c3g) {
    __shared__ float Z2[16 * 121];
    __shared__ float WS[160];
    int g = blockIdx.x >> 4, oc = blockIdx.x & 15;
    int tid = threadIdx.x;
    for (int idx = tid; idx < 16 * 120; idx += 128) {
        int ic = idx / 120, t = idx % 120;
        Z2[ic * 121 + t] = c2g[g * 1920 + idx];
    }
    for (int idx = tid; idx < 160; idx += 128) WS[idx] = w3c[oc * 160 + idx];
    __syncthreads();
    if (tid < 57) {
        float s = b3c[oc];
        #pragma unroll 4
        for (int ic = 0; ic < 16; ++ic) {
            const float* xr = &Z2[ic * 121];
            const float* wr = &WS[ic * 10];
            #pragma unroll
            for (int k = 0; k < 10; ++k) {
                int p = 2 * tid + k - 1;
                if (p >= 0 && p < 120) s += xr[p] * wr[k];
            }
        }
        c3g[g * 912 + oc * 57 + tid] = s >= 0.f ? s : 0.01f * s;
    }
}

// ================= heads: block = (g, head); fused maxpool + MLP + broadcast ===========
struct HeadW { const float *w1, *b1, *w2, *b2, *w3, *b3; };

__global__ __launch_bounds__(128) void k_heads(const float* __restrict__ c3g,
        HeadW hw0, HeadW hw1, HeadW hw2, float* __restrict__ out, int B) {
    __shared__ float Z3[16 * 57];
    __shared__ float ZF[80], HB[128], HC[128];
    __shared__ float partial[2];
    __shared__ float oval;
    int g = blockIdx.x / 3, hd = blockIdx.x % 3;
    int tid = threadIdx.x;
    const HeadW hw = (hd == 0) ? hw0 : (hd == 1) ? hw1 : hw2;
    for (int idx = tid; idx < 912; idx += 128) Z3[idx] = c3g[g * 912 + idx];
    __syncthreads();
    if (tid < 80) {                       // maxpool k=10 s=10 over L=57
        int ch = tid / 5, wd = tid % 5;
        const float* p = &Z3[ch * 57 + wd * 10];
        float m = p[0];
        #pragma unroll
        for (int k = 1; k < 10; ++k) m = fmaxf(m, p[k]);
        ZF[tid] = m;
    }
    __syncthreads();
    float s = hw.b1[tid];
    for (int k = 0; k < 80; ++k) s += ZF[k] * hw.w1[tid * 80 + k];
    HB[tid] = s >= 0.f ? s : 0.01f * s;
    __syncthreads();
    s = hw.b2[tid];
    for (int k = 0; k < 128; ++k) s += HB[k] * hw.w2[tid * 128 + k];
    HC[tid] = s >= 0.f ? s : 0.01f * s;
    __syncthreads();
    float p = HC[tid] * hw.w3[tid];
    #pragma unroll
    for (int o = 32; o > 0; o >>= 1) p += __shfl_down(p, o, 64);
    if ((tid & 63) == 0) partial[tid >> 6] = p;
    __syncthreads();
    if (tid == 0) {
        float o = partial[0] + partial[1] + hw.b3[0];
        o = (hd == 0) ? tanhf(o) : o;
        oval = o;
        if (g == 0) out[hd] = o;          // graph 0: the real result
    }
    __syncthreads();
    if (g == 1) {                          // zero-input constant -> graphs 1..B-1
        float o = oval;
        for (int gg = 1 + tid; gg < B; gg += 128) out[gg * 3 + hd] = o;
    }
}

extern "C" void kernel_launch(void* const* d_in, const int* in_sizes, int n_in,
                              void* d_out, int out_size, void* d_ws, size_t ws_size,
                              hipStream_t stream) {
    const float* x     = (const float*)d_in[0];
    const float* ea    = (const float*)d_in[1];
    const float* g1_W  = (const float*)d_in[2];
    const float* g1_We = (const float*)d_in[3];
    const float* g1_as = (const float*)d_in[4];
    const float* g1_ad = (const float*)d_in[5];
    const float* g1_ae = (const float*)d_in[6];
    const float* g1_b  = (const float*)d_in[7];
    const float* g2_W  = (const float*)d_in[8];
    const float* g2_We = (const float*)d_in[9];
    const float* g2_as = (const float*)d_in[10];
    const float* g2_ad = (const float*)d_in[11];
    const float* g2_ae = (const float*)d_in[12];
    const float* g2_b  = (const float*)d_in[13];
    const float* c1w = (const float*)d_in[14]; const float* c1b = (const float*)d_in[15];
    const float* c2w = (const float*)d_in[16]; const float* c2b = (const float*)d_in[17];
    const float* c3w = (const float*)d_in[18]; const float* c3b = (const float*)d_in[19];
    const int*   eidx = (const int*)d_in[38];
    float* out = (float*)d_out;

    const int N = in_sizes[0] / 5;
    const int E = in_sizes[38] / 2;
    const int B = out_size / 3;
    const int* src = eidx;
    const int* dst = eidx + E;

    // ---- workspace layout (float units, each offset rounded to 4) ----
    float* ws = (float*)d_ws;
    size_t o = 0;
    auto alloc = [&](size_t n) { float* p = ws + o; o = (o + n + 3) & ~(size_t)3; return p; };
    unsigned short* xpb = (unsigned short*)alloc((size_t)N * 48);  // [N][16][6] bf16
    float*    Hbuf  = alloc((size_t)N * 80);          // h1 bf16 (layer-2 input)
    float*    dterm = alloc((size_t)N * 16);
    int*      off   = (int*)alloc((size_t)N + 1);
    int*      off2  = (int*)alloc((size_t)N + 1);
    int*      bcnt  = (int*)alloc(1024);              // [all | keep] counts
    int*      boff  = (int*)alloc(516);
    int*      boff2 = (int*)alloc(516);
    int*      bcur  = (int*)alloc(512);
    uint4*    ebuf  = (uint4*)alloc((size_t)E * 4);   // 16B staging
    uint2*    erec  = (uint2*)alloc((size_t)(E + 4) * 2);   // 8B record + 4 pads
    uint2*    erec2 = (uint2*)alloc((size_t)(E + 4) * 2);   // keep-only list + 4 pads
    unsigned* psl   = (unsigned*)alloc(8 * 40000);    // 8 pool slices (encoded)
    float*    c1    = alloc(2 * 3952);                // conv1 out: 2 instances
    float*    c2g   = alloc(2 * 1920);
    float*    c3g   = alloc(2 * 912);

    const int BS = 256;
    auto blocks = [&](long long n) { return (int)((n + BS - 1) / BS); };
    const int NB = (N + 255) / 256;                   // coarse buckets (<= 512)
    const int TILES = (E + BIN_TILE - 1) / BIN_TILE;

    // ================= CSR build (dual edge lists) =================
    hipMemsetAsync(bcnt, 0, 1024 * 4, stream);
    hipMemsetAsync(psl, 0, 8 * 40000 * 4, stream);
    k_cnt512<<<TILES, 256, 0, stream>>>(dst, ea, bcnt, E, NB);
    k_scan512<<<1, 512, 0, stream>>>(bcnt, boff, bcur, boff2, off, off2,
                                     erec, erec2, NB, N, E);
    k_bin<<<TILES, 256, 0, stream>>>(src, dst, ea, bcur, ebuf, E, NB);
    k_perm2<<<NB, 256, 0, stream>>>(boff, boff2, ebuf, erec, erec2, off, off2, N);

    // ================= GAT layer 1 (all edges; h1 bf16 to Hbuf) =================
    k_proj5t<<<blocks((long long)N * 16), BS, 0, stream>>>(x, g1_W, g1_as, g1_ad,
                                                           xpb, dterm, N);
    k_gat<false><<<blocks((long long)N * 16), BS, 0, stream>>>(
        off, erec, dterm, g1_We, g1_ae, xpb, g1_b, (unsigned short*)Hbuf,
        x, psl, N);

    // ================= GAT layer 2 (keep-only edges; pool fused, h2 never stored) ======
    k_proj80t<<<(N + 127) / 128, 256, 0, stream>>>((const unsigned short*)Hbuf, g2_W,
                                                   g2_as, g2_ad, xpb, dterm, N);
    k_gat<true><<<blocks((long long)N * 16), BS, 0, stream>>>(
        off2, erec2, dterm, g2_We, g2_ae, xpb, g2_b, nullptr, x, psl, N);

    // ================= conv tower + heads: graph 0 + the zero-input constant ======
    k_conv1<<<32, 256, 0, stream>>>(psl, c1w, c1b, c1);
    k_conv2<<<32, 128, 0, stream>>>(c1, c2w, c2b, c2g);
    k_conv3<<<32, 128, 0, stream>>>(c2g, c3w, c3b, c3g);
    HeadW h0 = {(const float*)d_in[20], (const float*)d_in[21], (const float*)d_in[22],
                (const float*)d_in[23], (const float*)d_in[24], (const float*)d_in[25]};
    HeadW h1 = {(const float*)d_in[26], (const float*)d_in[27], (const float*)d_in[28],
                (const float*)d_in[29], (const float*)d_in[30], (const float*)d_in[31]};
    HeadW h2 = {(const float*)d_in[32], (const float*)d_in[33], (const float*)d_in[34],
                (const float*)d_in[35], (const float*)d_in[36], (const float*)d_in[37]};
    k_heads<<<6, 128, 0, stream>>>(c3g, h0, h1, h2, out, B);
}

// Round 19
// 405.128 us; speedup vs baseline: 1.1535x; 1.1535x over previous
//
#include <hip/hip_runtime.h>
#include <math.h>

#define DEV static __device__ __forceinline__

// ---- ordered-uint encoding for float atomic max ----
DEV unsigned fenc(float f) {
    unsigned u = __float_as_uint(f);
    return (u & 0x80000000u) ? ~u : (u | 0x80000000u);
}
DEV float fdec(unsigned u) {
    return __uint_as_float((u & 0x80000000u) ? (u ^ 0x80000000u) : ~u);
}
DEV void atomic_max_u32(unsigned* p, unsigned v) {
    __hip_atomic_fetch_max(p, v, __ATOMIC_RELAXED, __HIP_MEMORY_SCOPE_AGENT);
}
// ---- bf16 helpers (RNE) ----
DEV unsigned bf16(float f) {
    unsigned u = __float_as_uint(f);
    return (u + 0x7FFFu + ((u >> 16) & 1u)) >> 16;
}
DEV float unbf16(unsigned s) { return __uint_as_float(s << 16); }

// ================= layer-1 projection (K=5) fused with attn terms =================
// xpb: [N][16][6] bf16 record = {f0..f4, sterm}; 12B/head (192B/node), 4B-aligned.
__global__ void k_proj5t(const float* __restrict__ x, const float* __restrict__ W,
                         const float* __restrict__ a_s, const float* __restrict__ a_d,
                         unsigned short* __restrict__ xpb, float* __restrict__ dterm, int N) {
    int i = blockIdx.x * blockDim.x + threadIdx.x;   // n*16 + h
    if (i >= N * 16) return;
    int n = i >> 4, h = i & 15;
    float xr[5];
    #pragma unroll
    for (int j = 0; j < 5; ++j) xr[j] = x[(size_t)n * 5 + j];
    float o[5];
    #pragma unroll
    for (int c = 0; c < 5; ++c) {
        const float* wr = W + (size_t)(h * 5 + c) * 5;
        float s = 0.f;
        #pragma unroll
        for (int j = 0; j < 5; ++j) s += xr[j] * wr[j];
        o[c] = s;
    }
    float ss = 0.f, sd = 0.f;
    #pragma unroll
    for (int c = 0; c < 5; ++c) { ss += o[c] * a_s[h * 5 + c]; sd += o[c] * a_d[h * 5 + c]; }
    unsigned* p = (unsigned*)(xpb + (size_t)n * 96 + h * 6);
    p[0] = bf16(o[0]) | (bf16(o[1]) << 16);
    p[1] = bf16(o[2]) | (bf16(o[3]) << 16);
    p[2] = bf16(o[4]) | (bf16(ss) << 16);
    dterm[i] = sd;
}

// ================= layer-2 projection (K=80) : LDS-tiled GEMM, bf16 input =================
__global__ __launch_bounds__(256) void k_proj80t(
    const unsigned short* __restrict__ in,   // [N][80] bf16 (h1)
    const float* __restrict__ W,             // [80][80]
    const float* __restrict__ a_s, const float* __restrict__ a_d,
    unsigned short* __restrict__ xpb, float* __restrict__ dterm, int N) {
    __shared__ float XS[16 * 136];   // [kk][node]
    __shared__ float WS[16 * 81];    // [kk][oc]
    int tid = threadIdx.x;
    int n0 = blockIdx.x * 128;
    int h = tid & 15, ng = tid >> 4;

    float acc[8][5];
    #pragma unroll
    for (int j = 0; j < 8; ++j)
        #pragma unroll
        for (int c = 0; c < 5; ++c) acc[j][c] = 0.f;

    for (int k0 = 0; k0 < 80; k0 += 16) {
        __syncthreads();
        {   // stage XS: 8 bf16 per thread = one 16B load
            int r = tid >> 1;
            int halfk = (tid & 1) * 8;
            int n = n0 + r; if (n >= N) n = N - 1;
            const uint4 v = *(const uint4*)(in + (size_t)n * 80 + k0 + halfk);
            unsigned uu[4] = {v.x, v.y, v.z, v.w};
            #pragma unroll
            for (int j = 0; j < 4; ++j) {
                XS[(halfk + 2 * j)     * 136 + r] = unbf16(uu[j] & 0xffff);
                XS[(halfk + 2 * j + 1) * 136 + r] = unbf16(uu[j] >> 16);
            }
        }
        {   // stage WS
            #pragma unroll
            for (int i = 0; i < 5; ++i) {
                int j = tid + i * 256;
                int oc = j >> 4, kk = j & 15;
                WS[kk * 81 + oc] = W[(size_t)oc * 80 + k0 + kk];
            }
        }
        __syncthreads();
        #pragma unroll
        for (int kk = 0; kk < 16; ++kk) {
            float4 xa = *(const float4*)&XS[kk * 136 + ng * 8];
            float4 xb = *(const float4*)&XS[kk * 136 + ng * 8 + 4];
            float wv[5];
            #pragma unroll
            for (int c = 0; c < 5; ++c) wv[c] = WS[kk * 81 + h * 5 + c];
            float xv[8] = {xa.x, xa.y, xa.z, xa.w, xb.x, xb.y, xb.z, xb.w};
            #pragma unroll
            for (int j = 0; j < 8; ++j)
                #pragma unroll
                for (int c = 0; c < 5; ++c) acc[j][c] += xv[j] * wv[c];
        }
    }
    float as_[5], ad_[5];
    #pragma unroll
    for (int c = 0; c < 5; ++c) { as_[c] = a_s[h * 5 + c]; ad_[c] = a_d[h * 5 + c]; }
    #pragma unroll
    for (int j = 0; j < 8; ++j) {
        int n = n0 + ng * 8 + j;
        if (n < N) {
            float ss = 0.f, sd = 0.f;
            #pragma unroll
            for (int c = 0; c < 5; ++c) { ss += acc[j][c] * as_[c]; sd += acc[j][c] * ad_[c]; }
            unsigned* p = (unsigned*)(xpb + (size_t)n * 96 + h * 6);
            p[0] = bf16(acc[j][0]) | (bf16(acc[j][1]) << 16);
            p[1] = bf16(acc[j][2]) | (bf16(acc[j][3]) << 16);
            p[2] = bf16(acc[j][4]) | (bf16(ss) << 16);
            dterm[n * 16 + h] = sd;
        }
    }
}

// ================= CSR build: bucket counts (all + keep) -> scan -> bin -> LDS sort ====
#define BIN_TILE 4096
__global__ __launch_bounds__(256) void k_cnt512(const int* __restrict__ dst,
        const float* __restrict__ ea, int* __restrict__ bcnt, int E, int NB) {
    __shared__ int cnt[512], cnt2[512];
    int tid = threadIdx.x;
    for (int b = tid; b < NB; b += 256) { cnt[b] = 0; cnt2[b] = 0; }
    __syncthreads();
    int e0 = blockIdx.x * BIN_TILE;
    #pragma unroll
    for (int k = 0; k < BIN_TILE / 256; ++k) {
        int e = e0 + k * 256 + tid;
        if (e < E) {
            int b = ((unsigned)dst[e]) >> 8;
            atomicAdd(&cnt[b], 1);
            if (ea[2 * e] > 1.0f) atomicAdd(&cnt2[b], 1);
        }
    }
    __syncthreads();
    for (int b = tid; b < NB; b += 256) {
        if (cnt[b])  __hip_atomic_fetch_add(&bcnt[b], cnt[b], __ATOMIC_RELAXED, __HIP_MEMORY_SCOPE_AGENT);
        if (cnt2[b]) __hip_atomic_fetch_add(&bcnt[512 + b], cnt2[b], __ATOMIC_RELAXED, __HIP_MEMORY_SCOPE_AGENT);
    }
}

// single block: scan both count arrays; seed boff/bcur/boff2; write pads + off[N]/off2[N].
__global__ void k_scan512(const int* __restrict__ bcnt,
        int* __restrict__ boff, int* __restrict__ bcur, int* __restrict__ boff2,
        int* __restrict__ off, int* __restrict__ off2,
        uint2* __restrict__ erec, uint2* __restrict__ erec2, int NB, int N, int E) {
    __shared__ int sm[512], sm2[512];
    int t = threadIdx.x;
    int v  = (t < NB) ? bcnt[t] : 0;
    int v2 = (t < NB) ? bcnt[512 + t] : 0;
    sm[t] = v; sm2[t] = v2;
    __syncthreads();
    for (int s = 1; s < 512; s <<= 1) {
        int u = (t >= s) ? sm[t - s] : 0, u2 = (t >= s) ? sm2[t - s] : 0;
        __syncthreads();
        sm[t] += u; sm2[t] += u2;
        __syncthreads();
    }
    int excl = sm[t] - v, excl2 = sm2[t] - v2;
    if (t < NB) { boff[t] = excl; bcur[t] = excl; boff2[t] = excl2; }
    if (t == NB - 1) {
        int K = excl2 + v2;
        boff[NB] = excl + v; boff2[NB] = K;
        #pragma unroll
        for (int j = 0; j < 4; ++j) {                 // deep-pipeline pads
            erec[E + j] = make_uint2(0, 0);
            erec2[K + j] = make_uint2(0, 0);
        }
        off[N] = E; off2[N] = K;
    }
}

// bin edges into bucket-grouped ebuf. record: {src*192 | keep<<31, bf16ea pair, dst, 0}.
// keep = (ea0 > 1.0) evaluated EXACTLY in fp32 here.
__global__ __launch_bounds__(256) void k_bin(const int* __restrict__ src,
        const int* __restrict__ dst, const float* __restrict__ ea,
        int* __restrict__ bcur, uint4* __restrict__ ebuf, int E, int NB) {
    __shared__ int cnt[512];
    __shared__ int base[512];
    int tid = threadIdx.x;
    for (int b = tid; b < NB; b += 256) cnt[b] = 0;
    __syncthreads();
    int e0 = blockIdx.x * BIN_TILE;
    #pragma unroll
    for (int k = 0; k < BIN_TILE / 256; ++k) {
        int e = e0 + k * 256 + tid;
        if (e < E) atomicAdd(&cnt[((unsigned)dst[e]) >> 8], 1);
    }
    __syncthreads();
    for (int b = tid; b < NB; b += 256) {
        int c = cnt[b];
        base[b] = c ? __hip_atomic_fetch_add(&bcur[b], c, __ATOMIC_RELAXED,
                                             __HIP_MEMORY_SCOPE_AGENT) : 0;
        cnt[b] = 0;   // reuse as local cursor
    }
    __syncthreads();
    #pragma unroll
    for (int k = 0; k < BIN_TILE / 256; ++k) {
        int e = e0 + k * 256 + tid;
        if (e < E) {
            int d = dst[e];
            int b = ((unsigned)d) >> 8;
            int r = atomicAdd(&cnt[b], 1);
            float a0 = ea[2 * e], a1 = ea[2 * e + 1];
            unsigned ro = (unsigned)src[e] * 192u;          // byte row offset into xpb
            if (a0 > 1.0f) ro |= 0x80000000u;
            ebuf[base[b] + r] = make_uint4(ro, bf16(a0) | (bf16(a1) << 16), (unsigned)d, 0u);
        }
    }
}

// one block per bucket: per-node hists (all + keep) -> scans -> off/off2 -> scatter both.
__global__ __launch_bounds__(256) void k_perm2(const int* __restrict__ boff,
        const int* __restrict__ boff2, const uint4* __restrict__ ebuf,
        uint2* __restrict__ erec, uint2* __restrict__ erec2,
        int* __restrict__ off, int* __restrict__ off2, int N) {
    __shared__ int cA[256], sA[256], cB[256], sB[256];
    int b = blockIdx.x, tid = threadIdx.x;
    int d0 = b << 8;
    int s0 = boff[b], s1 = boff[b + 1];
    int s20 = boff2[b];
    cA[tid] = 0; cB[tid] = 0;
    __syncthreads();
    for (int i = s0 + tid; i < s1; i += 256) {
        uint4 r = ebuf[i];
        int l = (int)r.z - d0;
        atomicAdd(&cA[l], 1);
        if (r.x >> 31) atomicAdd(&cB[l], 1);
    }
    __syncthreads();
    int vA = cA[tid], vB = cB[tid];
    sA[tid] = vA; sB[tid] = vB;
    __syncthreads();
    for (int s = 1; s < 256; s <<= 1) {
        int uA = (tid >= s) ? sA[tid - s] : 0, uB = (tid >= s) ? sB[tid - s] : 0;
        __syncthreads();
        sA[tid] += uA; sB[tid] += uB;
        __syncthreads();
    }
    int eA = sA[tid] - vA, eB = sB[tid] - vB;
    if (d0 + tid < N) { off[d0 + tid] = s0 + eA; off2[d0 + tid] = s20 + eB; }
    cA[tid] = s0 + eA; cB[tid] = s20 + eB;   // cursors
    __syncthreads();
    for (int i = s0 + tid; i < s1; i += 256) {
        uint4 r = ebuf[i];
        int l = (int)r.z - d0;
        unsigned ro = r.x & 0x7fffffffu;
        int p = atomicAdd(&cA[l], 1);
        erec[p] = make_uint2(ro, r.y);
        if (r.x >> 31) {
            int p2 = atomicAdd(&cB[l], 1);
            erec2[p2] = make_uint2(ro, r.y);
        }
    }
}

// ================= fused GAT: branchless 2x-unrolled pipeline, one exp/edge =============
// record = {byte row offset into xpb, bf16 ea pair}; lists padded with 4 zero records.
// Writes bf16 h rows (coalesced stores — atomics here proved 10x worse, r5/r18).
__global__ void k_gat(const int* __restrict__ off, const uint2* __restrict__ erec,
                      const float* __restrict__ dterm,
                      const float* __restrict__ We, const float* __restrict__ a_e,
                      const unsigned short* __restrict__ xpb,
                      const float* __restrict__ bias, unsigned short* __restrict__ hout,
                      int N) {
    int i = blockIdx.x * blockDim.x + threadIdx.x;   // d*16 + h
    if (i >= N * 16) return;
    int d = i >> 4, h = i & 15;
    float q0 = 0.f, q1 = 0.f;
    #pragma unroll
    for (int c = 0; c < 5; ++c) {
        float ae = a_e[h * 5 + c];
        q0 += We[(h * 5 + c) * 2 + 0] * ae;
        q1 += We[(h * 5 + c) * 2 + 1] * ae;
    }
    float dt = dterm[i];
    const char* xb = (const char*)xpb;
    int hoff = h * 12;

    float m, den = 1.f, n0, n1, n2, n3, n4;
    {
        const uint3 v = *(const uint3*)(xb + d * 192 + hoff);
        n0 = unbf16(v.x & 0xffff); n1 = unbf16(v.x >> 16);
        n2 = unbf16(v.y & 0xffff); n3 = unbf16(v.y >> 16);
        n4 = unbf16(v.z & 0xffff);
        float sl = unbf16(v.z >> 16) + dt;
        m = fmaxf(sl, 0.2f * sl);
    }

    int e0 = off[d], e1 = off[d + 1];
    uint2 ra = erec[e0], rb = erec[e0 + 1];
    uint3 va = *(const uint3*)(xb + ra.x + hoff);
    uint3 vb = *(const uint3*)(xb + rb.x + hoff);
    for (int e = e0; e < e1; e += 2) {
        uint2 rc = erec[e + 2], rd = erec[e + 3];              // pads make these safe
        uint3 vc = *(const uint3*)(xb + rc.x + hoff);
        uint3 vd = *(const uint3*)(xb + rd.x + hoff);
        {   // edge A (always valid)
            float ea0 = unbf16(ra.y & 0xffff), ea1 = unbf16(ra.y >> 16);
            float st = unbf16(va.z >> 16);
            float al = st + dt + ea0 * q0 + ea1 * q1;
            al = fmaxf(al, 0.2f * al);
            bool gt = al > m;
            float t = __expf(-fabsf(al - m));
            float c = gt ? t : 1.f;
            float w = gt ? 1.f : t;
            m = fmaxf(m, al);
            den = den * c + w;
            n0 = n0 * c + w * unbf16(va.x & 0xffff);
            n1 = n1 * c + w * unbf16(va.x >> 16);
            n2 = n2 * c + w * unbf16(va.y & 0xffff);
            n3 = n3 * c + w * unbf16(va.y >> 16);
            n4 = n4 * c + w * unbf16(va.z & 0xffff);
        }
        if (e + 1 < e1) {   // edge B
            float ea0 = unbf16(rb.y & 0xffff), ea1 = unbf16(rb.y >> 16);
            float st = unbf16(vb.z >> 16);
            float al = st + dt + ea0 * q0 + ea1 * q1;
            al = fmaxf(al, 0.2f * al);
            bool gt = al > m;
            float t = __expf(-fabsf(al - m));
            float c = gt ? t : 1.f;
            float w = gt ? 1.f : t;
            m = fmaxf(m, al);
            den = den * c + w;
            n0 = n0 * c + w * unbf16(vb.x & 0xffff);
            n1 = n1 * c + w * unbf16(vb.x >> 16);
            n2 = n2 * c + w * unbf16(vb.y & 0xffff);
            n3 = n3 * c + w * unbf16(vb.y >> 16);
            n4 = n4 * c + w * unbf16(vb.z & 0xffff);
        }
        ra = rc; rb = rd; va = vc; vb = vd;
    }
    float inv = 1.0f / den;
    const float* br = bias + h * 5;
    unsigned short* orow = hout + (size_t)d * 80 + h * 5;
    orow[0] = (unsigned short)bf16(n0 * inv + br[0]);
    orow[1] = (unsigned short)bf16(n1 * inv + br[1]);
    orow[2] = (unsigned short)bf16(n2 * inv + br[2]);
    orow[3] = (unsigned short)bf16(n3 * inv + br[3]);
    orow[4] = (unsigned short)bf16(n4 * inv + br[4]);
}

// ---- scatter-max pool, 8-way XCD-sliced; channel-major (per-instruction coalesced) ----
__global__ void k_pool8(const float* __restrict__ x, const unsigned short* __restrict__ h2b,
                        unsigned* __restrict__ psl, int N) {
    int i = blockIdx.x * blockDim.x + threadIdx.x;   // n*80 + ch
    if (i >= N * 80) return;
    int n = i / 80, ch = i % 80;
    int t = (int)x[(size_t)n * 5 + 2];               // timing bin, 0..499
    unsigned* slice = psl + (size_t)(blockIdx.x & 7) * 40000;
    atomic_max_u32(&slice[t * 80 + ch], fenc(unbf16(h2b[i])));
}

// ================= conv1: 2 instances x 16 t-chunks; slice-reduce + decode fused =======
// NOTE: z[0][ic][p] = FLAT_pooled[ic*500 + p] (reference reshape quirk). Keep FLAT index.
__global__ __launch_bounds__(256) void k_conv1(const unsigned* __restrict__ psl,
        const float* __restrict__ w, const float* __restrict__ b,
        float* __restrict__ c1) {
    __shared__ float XS[80 * 44];        // window: p in [2*t0-1, 2*t0+39]
    __shared__ float WS[16 * 972];
    int gg = blockIdx.x >> 4, chunk = blockIdx.x & 15;
    int t0 = chunk * 16;
    int tid = threadIdx.x;
    for (int idx = tid; idx < 80 * 44; idx += 256) {
        int ic = idx / 44, j = idx % 44;
        int p = 2 * t0 - 1 + j;
        float v = 0.f;
        if (gg == 0 && j < 41 && p >= 0 && p < 500) {
            int jf = ic * 500 + p;                    // FLAT index (reshape quirk)
            unsigned u = 0u;
            #pragma unroll
            for (int s = 0; s < 8; ++s) u = max(u, psl[s * 40000 + jf]);
            v = (u == 0u) ? 0.f : fdec(u);
        }
        XS[idx] = v;
    }
    for (int idx = tid; idx < 12800; idx += 256) {
        int oc = idx / 800, r = idx % 800;
        int ic = r / 10, k = r % 10;
        WS[oc * 972 + ic * 12 + k] = w[idx];
    }
    __syncthreads();
    int oc = tid >> 4, tg = tid & 15;
    float acc = 0.f;
    for (int ic = 0; ic < 80; ++ic) {
        const float* xr = &XS[ic * 44 + 2 * tg];
        const float* wr = &WS[oc * 972 + ic * 12];
        #pragma unroll
        for (int k = 0; k < 10; ++k) acc += xr[k] * wr[k];
    }
    int t = t0 + tg;
    if (t < 247) {
        float s = acc + b[oc];
        c1[(size_t)gg * 3952 + oc * 247 + t] = s >= 0.f ? s : 0.01f * s;
    }
}

// ================= conv2: block = (g,oc), one t per thread =================
__global__ __launch_bounds__(128) void k_conv2(const float* __restrict__ c1,
        const float* __restrict__ w2c, const float* __restrict__ b2c,
        float* __restrict__ c2g) {
    __shared__ float Z1[16 * 248];
    __shared__ float WS[160];
    int g = blockIdx.x >> 4, oc = blockIdx.x & 15;
    int tid = threadIdx.x;
    for (int idx = tid; idx < 16 * 247; idx += 128) {
        int ic = idx / 247, t = idx % 247;
        Z1[ic * 248 + t] = c1[(size_t)g * 3952 + idx];
    }
    for (int idx = tid; idx < 160; idx += 128) WS[idx] = w2c[oc * 160 + idx];
    __syncthreads();
    if (tid < 120) {
        float s = b2c[oc];
        #pragma unroll 4
        for (int ic = 0; ic < 16; ++ic) {
            const float* xr = &Z1[ic * 248];
            const float* wr = &WS[ic * 10];
            #pragma unroll
            for (int k = 0; k < 10; ++k) {
                int p = 2 * tid + k - 1;
                if (p >= 0 && p < 247) s += xr[p] * wr[k];
            }
        }
        c2g[g * 1920 + oc * 120 + tid] = s >= 0.f ? s : 0.01f * s;
    }
}

// ================= conv3: block = (g,oc), one t per thread =================
__global__ __launch_bounds__(128) void k_conv3(const float* __restrict__ c2g,
        const float* __restrict__ w3c, const float* __restrict__ b3c,
        float* __restrict__ c3g) {
    __shared__ float Z2[16 * 121];
    __shared__ float WS[160];
    int g = blockIdx.x >> 4, oc = blockIdx.x & 15;
    int tid = threadIdx.x;
    for (int idx = tid; idx < 16 * 120; idx += 128) {
        int ic = idx / 120, t = idx % 120;
        Z2[ic * 121 + t] = c2g[g * 1920 + idx];
    }
    for (int idx = tid; idx < 160; idx += 128) WS[idx] = w3c[oc * 160 + idx];
    __syncthreads();
    if (tid < 57) {
        float s = b3c[oc];
        #pragma unroll 4
        for (int ic = 0; ic < 16; ++ic) {
            const float* xr = &Z2[ic * 121];
            const float* wr = &WS[ic * 10];
            #pragma unroll
            for (int k = 0; k < 10; ++k) {
                int p = 2 * tid + k - 1;
                if (p >= 0 && p < 120) s += xr[p] * wr[k];
            }
        }
        c3g[g * 912 + oc * 57 + tid] = s >= 0.f ? s : 0.01f * s;
    }
}

// ================= heads: block = (g, head); fused maxpool + MLP + broadcast ===========
struct HeadW { const float *w1, *b1, *w2, *b2, *w3, *b3; };

__global__ __launch_bounds__(128) void k_heads(const float* __restrict__ c3g,
        HeadW hw0, HeadW hw1, HeadW hw2, float* __restrict__ out, int B) {
    __shared__ float Z3[16 * 57];
    __shared__ float ZF[80], HB[128], HC[128];
    __shared__ float partial[2];
    __shared__ float oval;
    int g = blockIdx.x / 3, hd = blockIdx.x % 3;
    int tid = threadIdx.x;
    const HeadW hw = (hd == 0) ? hw0 : (hd == 1) ? hw1 : hw2;
    for (int idx = tid; idx < 912; idx += 128) Z3[idx] = c3g[g * 912 + idx];
    __syncthreads();
    if (tid < 80) {                       // maxpool k=10 s=10 over L=57
        int ch = tid / 5, wd = tid % 5;
        const float* p = &Z3[ch * 57 + wd * 10];
        float m = p[0];
        #pragma unroll
        for (int k = 1; k < 10; ++k) m = fmaxf(m, p[k]);
        ZF[tid] = m;
    }
    __syncthreads();
    float s = hw.b1[tid];
    for (int k = 0; k < 80; ++k) s += ZF[k] * hw.w1[tid * 80 + k];
    HB[tid] = s >= 0.f ? s : 0.01f * s;
    __syncthreads();
    s = hw.b2[tid];
    for (int k = 0; k < 128; ++k) s += HB[k] * hw.w2[tid * 128 + k];
    HC[tid] = s >= 0.f ? s : 0.01f * s;
    __syncthreads();
    float p = HC[tid] * hw.w3[tid];
    #pragma unroll
    for (int o = 32; o > 0; o >>= 1) p += __shfl_down(p, o, 64);
    if ((tid & 63) == 0) partial[tid >> 6] = p;
    __syncthreads();
    if (tid == 0) {
        float o = partial[0] + partial[1] + hw.b3[0];
        o = (hd == 0) ? tanhf(o) : o;
        oval = o;
        if (g == 0) out[hd] = o;          // graph 0: the real result
    }
    __syncthreads();
    if (g == 1) {                          // zero-input constant -> graphs 1..B-1
        float o = oval;
        for (int gg = 1 + tid; gg < B; gg += 128) out[gg * 3 + hd] = o;
    }
}

extern "C" void kernel_launch(void* const* d_in, const int* in_sizes, int n_in,
                              void* d_out, int out_size, void* d_ws, size_t ws_size,
                              hipStream_t stream) {
    const float* x     = (const float*)d_in[0];
    const float* ea    = (const float*)d_in[1];
    const float* g1_W  = (const float*)d_in[2];
    const float* g1_We = (const float*)d_in[3];
    const float* g1_as = (const float*)d_in[4];
    const float* g1_ad = (const float*)d_in[5];
    const float* g1_ae = (const float*)d_in[6];
    const float* g1_b  = (const float*)d_in[7];
    const float* g2_W  = (const float*)d_in[8];
    const float* g2_We = (const float*)d_in[9];
    const float* g2_as = (const float*)d_in[10];
    const float* g2_ad = (const float*)d_in[11];
    const float* g2_ae = (const float*)d_in[12];
    const float* g2_b  = (const float*)d_in[13];
    const float* c1w = (const float*)d_in[14]; const float* c1b = (const float*)d_in[15];
    const float* c2w = (const float*)d_in[16]; const float* c2b = (const float*)d_in[17];
    const float* c3w = (const float*)d_in[18]; const float* c3b = (const float*)d_in[19];
    const int*   eidx = (const int*)d_in[38];
    float* out = (float*)d_out;

    const int N = in_sizes[0] / 5;
    const int E = in_sizes[38] / 2;
    const int B = out_size / 3;
    const int* src = eidx;
    const int* dst = eidx + E;

    // ---- workspace layout (float units, each offset rounded to 4) ----
    float* ws = (float*)d_ws;
    size_t o = 0;
    auto alloc = [&](size_t n) { float* p = ws + o; o = (o + n + 3) & ~(size_t)3; return p; };
    unsigned short* xpb = (unsigned short*)alloc((size_t)N * 48);  // [N][16][6] bf16
    float*    Hbuf  = alloc((size_t)N * 80);          // h1 bf16, then h2 bf16 (reused)
    float*    dterm = alloc((size_t)N * 16);
    int*      off   = (int*)alloc((size_t)N + 1);
    int*      off2  = (int*)alloc((size_t)N + 1);
    int*      bcnt  = (int*)alloc(1024);              // [all | keep] counts
    int*      boff  = (int*)alloc(516);
    int*      boff2 = (int*)alloc(516);
    int*      bcur  = (int*)alloc(512);
    uint4*    ebuf  = (uint4*)alloc((size_t)E * 4);   // 16B staging
    uint2*    erec  = (uint2*)alloc((size_t)(E + 4) * 2);   // 8B record + 4 pads
    uint2*    erec2 = (uint2*)alloc((size_t)(E + 4) * 2);   // keep-only list + 4 pads
    unsigned* psl   = (unsigned*)alloc(8 * 40000);    // 8 pool slices (encoded)
    float*    c1    = alloc(2 * 3952);                // conv1 out: 2 instances
    float*    c2g   = alloc(2 * 1920);
    float*    c3g   = alloc(2 * 912);

    const int BS = 256;
    auto blocks = [&](long long n) { return (int)((n + BS - 1) / BS); };
    const int NB = (N + 255) / 256;                   // coarse buckets (<= 512)
    const int TILES = (E + BIN_TILE - 1) / BIN_TILE;

    // ================= CSR build (dual edge lists) =================
    hipMemsetAsync(bcnt, 0, 1024 * 4, stream);
    hipMemsetAsync(psl, 0, 8 * 40000 * 4, stream);
    k_cnt512<<<TILES, 256, 0, stream>>>(dst, ea, bcnt, E, NB);
    k_scan512<<<1, 512, 0, stream>>>(bcnt, boff, bcur, boff2, off, off2,
                                     erec, erec2, NB, N, E);
    k_bin<<<TILES, 256, 0, stream>>>(src, dst, ea, bcur, ebuf, E, NB);
    k_perm2<<<NB, 256, 0, stream>>>(boff, boff2, ebuf, erec, erec2, off, off2, N);

    // ================= GAT layer 1 (all edges; h1 bf16) =================
    k_proj5t<<<blocks((long long)N * 16), BS, 0, stream>>>(x, g1_W, g1_as, g1_ad,
                                                           xpb, dterm, N);
    k_gat<<<blocks((long long)N * 16), BS, 0, stream>>>(
        off, erec, dterm, g1_We, g1_ae, xpb, g1_b, (unsigned short*)Hbuf, N);

    // ================= GAT layer 2 (keep-only edges; h2 bf16) =================
    k_proj80t<<<(N + 127) / 128, 256, 0, stream>>>((const unsigned short*)Hbuf, g2_W,
                                                   g2_as, g2_ad, xpb, dterm, N);
    k_gat<<<blocks((long long)N * 16), BS, 0, stream>>>(
        off2, erec2, dterm, g2_We, g2_ae, xpb, g2_b, (unsigned short*)Hbuf, N);

    // ================= pooling (8-way sliced, channel-major) =================
    k_pool8<<<blocks((long long)N * 80), BS, 0, stream>>>(x, (const unsigned short*)Hbuf,
                                                          psl, N);

    // ================= conv tower + heads: graph 0 + the zero-input constant ======
    k_conv1<<<32, 256, 0, stream>>>(psl, c1w, c1b, c1);
    k_conv2<<<32, 128, 0, stream>>>(c1, c2w, c2b, c2g);
    k_conv3<<<32, 128, 0, stream>>>(c2g, c3w, c3b, c3g);
    HeadW h0 = {(const float*)d_in[20], (const float*)d_in[21], (const float*)d_in[22],
                (const float*)d_in[23], (const float*)d_in[24], (const float*)d_in[25]};
    HeadW h1 = {(const float*)d_in[26], (const float*)d_in[27], (const float*)d_in[28],
                (const float*)d_in[29], (const float*)d_in[30], (const float*)d_in[31]};
    HeadW h2 = {(const float*)d_in[32], (const float*)d_in[33], (const float*)d_in[34],
                (const float*)d_in[35], (const float*)d_in[36], (const float*)d_in[37]};
    k_heads<<<6, 128, 0, stream>>>(c3g, h0, h1, h2, out, B);
}